// Round 4
// baseline (103.889 us; speedup 1.0000x reference)
//
#include <hip/hip_runtime.h>
#include <stdint.h>
#include <math.h>

#define BSZ 4096
#define DIM 768
#define TEMP 0.07f

typedef short short8 __attribute__((ext_vector_type(8)));
typedef float f32x4 __attribute__((ext_vector_type(4)));

// ---------- helpers ----------

__device__ __forceinline__ uint16_t f2bf(float f) {
  uint32_t u = __float_as_uint(f);
  uint32_t r = (u + 0x7FFFu + ((u >> 16) & 1u)) >> 16;  // RNE
  return (uint16_t)r;
}

__device__ __forceinline__ void gll16(const void* g, void* l) {
  __builtin_amdgcn_global_load_lds(
      (__attribute__((address_space(1))) void*)(uintptr_t)g,
      (__attribute__((address_space(3))) void*)l,
      16, 0, 0);
}

// branchy sorted-desc top-5 insert (kept for tiny k_merge only)
__device__ __forceinline__ void ins5(float v, float& a, float& b, float& c,
                                     float& d, float& e) {
  if (v > e) {
    e = v;
    if (e > d) { float t = d; d = e; e = t;
      if (d > c) { t = c; c = d; d = t;
        if (c > b) { t = b; b = c; c = t;
          if (b > a) { t = a; a = b; b = t; } } } }
  }
}

// branchless sorted-desc top-5 insert: 9 v_min/v_max, no divergence
__device__ __forceinline__ void sins5(float v, float& a, float& b, float& c,
                                      float& d, float& e) {
  float t;
  t = fmaxf(a, v); v = fminf(a, v); a = t;
  t = fmaxf(b, v); v = fminf(b, v); b = t;
  t = fmaxf(c, v); v = fminf(c, v); c = t;
  t = fmaxf(d, v); v = fminf(d, v); d = t;
  e = fmaxf(e, v);
}

// ---------- K1: normalize + cast to bf16 ----------
__global__ __launch_bounds__(256) void k_norm(const float* __restrict__ text,
                                              const float* __restrict__ table,
                                              uint16_t* __restrict__ tn,
                                              uint16_t* __restrict__ zn) {
  int row = blockIdx.x & (BSZ - 1);
  bool isTable = blockIdx.x >= BSZ;
  const float* src = (isTable ? table : text) + (size_t)row * DIM;
  uint16_t* dst = (isTable ? zn : tn) + (size_t)row * DIM;
  int tid = threadIdx.x;

  float x0 = src[tid];
  float x1 = src[tid + 256];
  float x2 = src[tid + 512];
  float ss = x0 * x0 + x1 * x1 + x2 * x2;
  #pragma unroll
  for (int off = 32; off >= 1; off >>= 1) ss += __shfl_xor(ss, off);
  __shared__ float wss[4];
  if ((tid & 63) == 0) wss[tid >> 6] = ss;
  __syncthreads();
  float inv = rsqrtf(wss[0] + wss[1] + wss[2] + wss[3]);
  dst[tid]       = f2bf(x0 * inv);
  dst[tid + 256] = f2bf(x1 * inv);
  dst[tid + 512] = f2bf(x2 * inv);
}

// ---------- K2: sim = Zn @ Tn^T  (128x128 tile, BK=64, counted-vmcnt pipeline)
// 256 threads = 4 waves (2M x 2N), wave tile 64x64.
// LDS 64 KiB -> 2 blocks/CU (the round-3 256^2 version was 1 block/CU and
// barrier-lockstep; inter-block overlap is the m114 mechanism).
// LDS per buffer (32 KiB): A @0 (8 kc-slabs x 128 rows x 16B), B @16384 same.
// A rows stored PERMUTED: pos = (r&31) | ((r&32)<<1) | ((r&64)>>1)  (involution)
//   -> phase A (m0-1) reads only pos 0..63 (unit 0), phase B (m2-3) pos 64..127.
// Staging per tile: 8 gll16/thread; post-phaseA: A-unit0 + all B (6), post-phaseB:
// A-unit1 (2); vmcnt(8) retires exactly the previous tile's 8.
// Grid 1024, XCD-swizzled: xcd = bid&7 owns a 16x8 tile region (resident ~3MB < L2).
__global__ __launch_bounds__(256, 2) void k_gemm(const uint16_t* __restrict__ Zb,
                                                 const uint16_t* __restrict__ Tb,
                                                 float* __restrict__ sim) {
  extern __shared__ __attribute__((aligned(16))) char lds[];

  int tid = threadIdx.x;
  int wave = tid >> 6, lane = tid & 63;
  int wm = wave >> 1, wn = wave & 1;

  int bid = blockIdx.x;
  int xcd = bid & 7, li = bid >> 3;
  int trow = ((xcd >> 2) << 4) + (li >> 3);   // 0..31
  int tcol = ((xcd & 3) << 3) + (li & 7);     // 0..31
  int brow = trow << 7, bcol = tcol << 7;

  f32x4 acc[4][4] = {};

  const uint16_t* gA = Zb + (size_t)brow * DIM;
  const uint16_t* gB = Tb + (size_t)bcol * DIM;

  int c0 = wave, c1 = wave + 4;                 // owned kc slabs
  int rA0 = (lane & 31) | ((lane & 32) << 1);   // global A row for unit-0 lane
  int kqg = lane >> 4;                          // 0..3
  int cbyte = ((wn << 6) + (lane & 15)) << 4;   // B row base byte in kc-slab

  int rbyteM[4];                                // permuted A frag offsets per m
  #pragma unroll
  for (int m = 0; m < 4; ++m) {
    int row = (wm << 6) + (m << 4) + (lane & 15);
    int pos = (row & 31) | ((row & 32) << 1) | ((row & 64) >> 1);
    rbyteM[m] = pos << 4;
  }

  auto SA = [&](int t, int bb, int c, int u) {
    gll16(gA + (size_t)(rA0 + u * 32) * DIM + t * 64 + c * 8,
          lds + bb + (c << 11) + (u << 10));
  };
  auto SB = [&](int t, int bb, int c, int u) {
    gll16(gB + (size_t)((u << 6) + lane) * DIM + t * 64 + c * 8,
          lds + bb + 16384 + (c << 11) + (u << 10));
  };

  auto LOADB = [&](int bb, short8 (&bf)[2][4]) {
    #pragma unroll
    for (int ks = 0; ks < 2; ++ks) {
      const char* Bb = lds + bb + 16384 + (((ks << 2) + kqg) << 11);
      #pragma unroll
      for (int n = 0; n < 4; ++n)
        bf[ks][n] = *(const short8*)(Bb + cbyte + (n << 8));
    }
  };
  auto PHASE = [&](int bb, int mlo, short8 (&bf)[2][4]) {
    __builtin_amdgcn_s_setprio(1);
    #pragma unroll
    for (int ks = 0; ks < 2; ++ks) {
      const char* Ab = lds + bb + (((ks << 2) + kqg) << 11);
      #pragma unroll
      for (int mm = 0; mm < 2; ++mm) {
        int m = mlo + mm;
        short8 af = *(const short8*)(Ab + rbyteM[m]);
        #pragma unroll
        for (int n = 0; n < 4; ++n)
          acc[m][n] = __builtin_amdgcn_mfma_f32_16x16x32_bf16(
              af, bf[ks][n], acc[m][n], 0, 0, 0);
      }
    }
    __builtin_amdgcn_s_setprio(0);
  };

  auto STAGEALL = [&](int t, int bb) {
    SA(t, bb, c0, 0); SA(t, bb, c0, 1); SA(t, bb, c1, 0); SA(t, bb, c1, 1);
    SB(t, bb, c0, 0); SB(t, bb, c0, 1); SB(t, bb, c1, 0); SB(t, bb, c1, 1);
  };

  // ---- prologue: stage tiles 0 (buf0) and 1 (buf1); land 0, keep 1 in flight
  STAGEALL(0, 0);
  STAGEALL(1, 32768);
  asm volatile("s_waitcnt vmcnt(8)" ::: "memory");
  __builtin_amdgcn_s_barrier();

  // ---- main loop: tiles 0..9, staging tiles 2..11
  #pragma unroll 2
  for (int t = 0; t < 10; ++t) {
    int bb = (t & 1) << 15;
    short8 bf[2][4];
    LOADB(bb, bf);
    PHASE(bb, 0, bf);           // reads A pos 0..63 only
    __builtin_amdgcn_s_barrier();
    SA(t + 2, bb, c0, 0); SA(t + 2, bb, c1, 0);       // A unit-0 (dead)
    SB(t + 2, bb, c0, 0); SB(t + 2, bb, c0, 1);       // B fully in regs
    SB(t + 2, bb, c1, 0); SB(t + 2, bb, c1, 1);
    PHASE(bb, 2, bf);           // reads A pos 64..127 only
    __builtin_amdgcn_s_barrier();
    SA(t + 2, bb, c0, 1); SA(t + 2, bb, c1, 1);       // A unit-1
    asm volatile("s_waitcnt vmcnt(8)" ::: "memory");  // retire tile t+1's 8 loads
    __builtin_amdgcn_s_barrier();
  }

  // ---- epilogue tiles: 10 (buf0), 11 (buf1) — no further staging
  {
    short8 bf[2][4];
    LOADB(0, bf);
    PHASE(0, 0, bf);
    PHASE(0, 2, bf);
  }
  asm volatile("s_waitcnt vmcnt(0)" ::: "memory");
  __builtin_amdgcn_s_barrier();
  {
    short8 bf[2][4];
    LOADB(32768, bf);
    PHASE(32768, 0, bf);
    PHASE(32768, 2, bf);
  }

  // epilogue: C/D layout col=lane&15, row=(lane>>4)*4+reg
  int crow0 = brow + (wm << 6) + ((lane >> 4) << 2);
  int ccol0 = bcol + (wn << 6) + (lane & 15);
  #pragma unroll
  for (int m = 0; m < 4; ++m)
    #pragma unroll
    for (int n = 0; n < 4; ++n)
      #pragma unroll
      for (int r = 0; r < 4; ++r)
        sim[(size_t)(crow0 + m * 16 + r) * BSZ + (ccol0 + n * 16)] = acc[m][n][r];
}

// ---------- K3: tile pass — row & col partial top-5 (branchless, b128, 1 barrier)
// 1024 blocks, 256 threads, 128x128 tile in 64 KiB LDS.
__global__ __launch_bounds__(256) void k_tile(const float* __restrict__ sim,
                                              float* __restrict__ rp,
                                              float* __restrict__ cp) {
  extern __shared__ float l32[];  // 128*128 floats = 64 KiB
  int tid = threadIdx.x;
  int tr = blockIdx.x >> 5, tc = blockIdx.x & 31;
  int row0 = tr << 7, col0 = tc << 7;
  bool diag = (tr == tc);

  // ---- stage: 16 x f32x4 coalesced loads
  int q = tid & 31;   // chunk col 0..31
  int g = tid >> 5;   // row group 0..7
  const float* gsrc = sim + (size_t)(row0 + (g << 4)) * BSZ + col0 + (q << 2);

  f32x4 v[16];
  #pragma unroll
  for (int k = 0; k < 16; ++k)
    v[k] = *(const f32x4*)(gsrc + (size_t)k * BSZ);

  #pragma unroll
  for (int k = 0; k < 16; ++k) {
    int r = (g << 4) + k;
    if (diag && (r >> 2) == q) v[k][r & 3] = -1e30f;  // mask diagonal
    *(f32x4*)(l32 + (r << 7) + ((q ^ (r & 7)) << 2)) = v[k];
  }
  __syncthreads();

  // ---- row scan: 2 threads/row, 64 cols each via 16 x b128
  {
    int row = tid >> 1, h = tid & 1;
    int rx = row & 7;
    const float* rb = l32 + (row << 7);
    float a0 = -1e30f, a1 = -1e30f, a2 = -1e30f, a3 = -1e30f, a4 = -1e30f;
    #pragma unroll
    for (int j = 0; j < 16; ++j) {
      int c16 = (h << 4) + j;
      f32x4 x = *(const f32x4*)(rb + ((c16 ^ rx) << 2));
      sins5(x[0], a0, a1, a2, a3, a4);
      sins5(x[1], a0, a1, a2, a3, a4);
      sins5(x[2], a0, a1, a2, a3, a4);
      sins5(x[3], a0, a1, a2, a3, a4);
    }
    float b0 = __shfl_xor(a0, 1), b1 = __shfl_xor(a1, 1),
          b2 = __shfl_xor(a2, 1), b3 = __shfl_xor(a3, 1),
          b4 = __shfl_xor(a4, 1);
    sins5(b0, a0, a1, a2, a3, a4);
    sins5(b1, a0, a1, a2, a3, a4);
    sins5(b2, a0, a1, a2, a3, a4);
    sins5(b3, a0, a1, a2, a3, a4);
    sins5(b4, a0, a1, a2, a3, a4);
    if (h == 0) {
      float* pr = rp + ((size_t)(row0 + row) * 32 + tc) * 5;
      pr[0] = a0; pr[1] = a1; pr[2] = a2; pr[3] = a3; pr[4] = a4;
    }
  }

  // ---- col scan: 2 threads/col, 64 rows each via b32
  {
    int c = tid >> 1, hf = tid & 1;
    int cc = c >> 2, cw = c & 3;
    float a0 = -1e30f, a1 = -1e30f, a2 = -1e30f, a3 = -1e30f, a4 = -1e30f;
    #pragma unroll 8
    for (int k = 0; k < 64; ++k) {
      int r = (hf << 6) + k;
      float x = l32[(r << 7) + (((cc ^ (r & 7)) << 2) | cw)];
      sins5(x, a0, a1, a2, a3, a4);
    }
    float b0 = __shfl_xor(a0, 1), b1 = __shfl_xor(a1, 1),
          b2 = __shfl_xor(a2, 1), b3 = __shfl_xor(a3, 1),
          b4 = __shfl_xor(a4, 1);
    sins5(b0, a0, a1, a2, a3, a4);
    sins5(b1, a0, a1, a2, a3, a4);
    sins5(b2, a0, a1, a2, a3, a4);
    sins5(b3, a0, a1, a2, a3, a4);
    sins5(b4, a0, a1, a2, a3, a4);
    if (hf == 0) {
      float* pc = cp + ((size_t)(col0 + c) * 32 + tr) * 5;
      pc[0] = a0; pc[1] = a1; pc[2] = a2; pc[3] = a3; pc[4] = a4;
    }
  }
}

// ---------- K4: merge partials (wave per line) + loss ----------
__global__ __launch_bounds__(256) void k_merge(const float* __restrict__ sim,
                                               const float* __restrict__ rp,
                                               const float* __restrict__ cp,
                                               float* __restrict__ lossbuf) {
  int wave = threadIdx.x >> 6, lane = threadIdx.x & 63;
  int wid = blockIdx.x * 4 + wave;
  bool isCol = wid >= BSZ;
  int line = isCol ? wid - BSZ : wid;
  const float* src = (isCol ? cp : rp) + (size_t)line * 160;

  float t0 = -1e30f, t1 = -1e30f, t2 = -1e30f, t3 = -1e30f, t4 = -1e30f;
  ins5(src[lane], t0, t1, t2, t3, t4);
  ins5(src[lane + 64], t0, t1, t2, t3, t4);
  if (lane < 32) ins5(src[lane + 128], t0, t1, t2, t3, t4);

  float top[5];
  #pragma unroll
  for (int e = 0; e < 5; e++) {
    float m = t0;
    #pragma unroll
    for (int off = 32; off >= 1; off >>= 1) m = fmaxf(m, __shfl_xor(m, off));
    unsigned long long msk = __ballot(t0 == m);
    int owner = __ffsll(msk) - 1;
    if (lane == owner) { t0 = t1; t1 = t2; t2 = t3; t3 = t4; t4 = -1e30f; }
    top[e] = m;
  }

  if (lane == 0) {
    float pos = sim[(size_t)line * BSZ + line] / TEMP;
    float l0 = top[0] / TEMP, l1 = top[1] / TEMP, l2 = top[2] / TEMP,
          l3 = top[3] / TEMP, l4 = top[4] / TEMP;
    float mx = fmaxf(pos, fmaxf(fmaxf(l0, l1), fmaxf(fmaxf(l2, l3), l4)));
    float s = expf(pos - mx) + expf(l0 - mx) + expf(l1 - mx) +
              expf(l2 - mx) + expf(l3 - mx) + expf(l4 - mx);
    lossbuf[wid] = mx + logf(s) - pos;
  }
}

// ---------- K5: final reduction ----------
__global__ __launch_bounds__(256) void k_reduce(const float* __restrict__ losses,
                                                float* __restrict__ out) {
  int tid = threadIdx.x;
  float s = 0.f;
  for (int i = tid; i < 2 * BSZ; i += 256) s += losses[i];
  #pragma unroll
  for (int off = 32; off >= 1; off >>= 1) s += __shfl_xor(s, off);
  __shared__ float wss[4];
  if ((tid & 63) == 0) wss[tid >> 6] = s;
  __syncthreads();
  if (tid == 0) out[0] = (wss[0] + wss[1] + wss[2] + wss[3]) / (2.0f * BSZ);
}

// ---------- launcher ----------
extern "C" void kernel_launch(void* const* d_in, const int* in_sizes, int n_in,
                              void* d_out, int out_size, void* d_ws, size_t ws_size,
                              hipStream_t stream) {
  const float* text = (const float*)d_in[0];
  const float* table = (const float*)d_in[1];
  float* out = (float*)d_out;
  float* sim = out + 1;  // d_out = [loss, sim(4096x4096)]

  uint16_t* Zb = (uint16_t*)d_ws;
  uint16_t* Tb = Zb + (size_t)BSZ * DIM;
  float* lossbuf = (float*)(Tb + (size_t)BSZ * DIM);  // 2*BSZ floats

  // rp/cp alias the Zb/Tb region (dead after k_gemm; stream-ordered).
  float* rp = (float*)d_ws;                  // [4096][32][5]
  float* cp = rp + (size_t)BSZ * 32 * 5;     // [4096][32][5]

  k_norm<<<2 * BSZ, 256, 0, stream>>>(text, table, Tb, Zb);
  k_gemm<<<(BSZ / 128) * (BSZ / 128), 256, 65536, stream>>>(Zb, Tb, sim);
  k_tile<<<32 * 32, 256, 65536, stream>>>(sim, rp, cp);
  k_merge<<<2 * BSZ / 4, 256, 0, stream>>>(sim, rp, cp, lossbuf);
  k_reduce<<<1, 256, 0, stream>>>(lossbuf, out);
}

// Round 5
// 89.424 us; speedup vs baseline: 1.1618x; 1.1618x over previous
//
#include <hip/hip_runtime.h>
#include <stdint.h>
#include <math.h>

#define BSZ 4096
#define DIM 768
#define TEMP 0.07f

typedef short short8 __attribute__((ext_vector_type(8)));
typedef float f32x4 __attribute__((ext_vector_type(4)));

// ---------- helpers ----------

__device__ __forceinline__ uint16_t f2bf(float f) {
  uint32_t u = __float_as_uint(f);
  uint32_t r = (u + 0x7FFFu + ((u >> 16) & 1u)) >> 16;  // RNE
  return (uint16_t)r;
}

__device__ __forceinline__ void gll16(const void* g, void* l) {
  __builtin_amdgcn_global_load_lds(
      (__attribute__((address_space(1))) void*)(uintptr_t)g,
      (__attribute__((address_space(3))) void*)l,
      16, 0, 0);
}

// branchy sorted-desc top-5 insert (kept for tiny k_merge only)
__device__ __forceinline__ void ins5(float v, float& a, float& b, float& c,
                                     float& d, float& e) {
  if (v > e) {
    e = v;
    if (e > d) { float t = d; d = e; e = t;
      if (d > c) { t = c; c = d; d = t;
        if (c > b) { t = b; b = c; c = t;
          if (b > a) { t = a; a = b; b = t; } } } }
  }
}

// branchless sorted-desc top-5 insert: 9 v_min/v_max, no divergence
__device__ __forceinline__ void sins5(float v, float& a, float& b, float& c,
                                      float& d, float& e) {
  float t;
  t = fmaxf(a, v); v = fminf(a, v); a = t;
  t = fmaxf(b, v); v = fminf(b, v); b = t;
  t = fmaxf(c, v); v = fminf(c, v); c = t;
  t = fmaxf(d, v); v = fminf(d, v); d = t;
  e = fmaxf(e, v);
}

// ---------- K1: normalize + cast to bf16 ----------
__global__ __launch_bounds__(256) void k_norm(const float* __restrict__ text,
                                              const float* __restrict__ table,
                                              uint16_t* __restrict__ tn,
                                              uint16_t* __restrict__ zn) {
  int row = blockIdx.x & (BSZ - 1);
  bool isTable = blockIdx.x >= BSZ;
  const float* src = (isTable ? table : text) + (size_t)row * DIM;
  uint16_t* dst = (isTable ? zn : tn) + (size_t)row * DIM;
  int tid = threadIdx.x;

  float x0 = src[tid];
  float x1 = src[tid + 256];
  float x2 = src[tid + 512];
  float ss = x0 * x0 + x1 * x1 + x2 * x2;
  #pragma unroll
  for (int off = 32; off >= 1; off >>= 1) ss += __shfl_xor(ss, off);
  __shared__ float wss[4];
  if ((tid & 63) == 0) wss[tid >> 6] = ss;
  __syncthreads();
  float inv = rsqrtf(wss[0] + wss[1] + wss[2] + wss[3]);
  dst[tid]       = f2bf(x0 * inv);
  dst[tid + 256] = f2bf(x1 * inv);
  dst[tid + 512] = f2bf(x2 * inv);
}

// ---------- K2: sim = Zn @ Tn^T  (256x256 tile, BK=64, 4-phase interleave)
// 512 threads = 8 waves (2M x 4N), wave tile 128x64. LDS 128 KiB:
// buf0 A @0, B @32768; buf1 A @65536, B @98304; per operand [kc 0..7][row 0..255][16B].
// Wave w stages kc-slab w; SA/SB(rg) = 1 gll16/thread for rows rg*64..+63.
//
// Per K-tile, 4 phases (m201 T3+T4 pattern), each:
//   {ds_read quadrant ; issue stage gll ; barrier ; lgkmcnt(0) ; setprio 16xMFMA ; barrier}
// Region liveness: B (all read p0, reg-resident) restaged p1; A rg0/rg2 (read p0-p1)
// restaged p2; A rg1/rg3 (read p2-p3) restaged at NEXT tile's p0.
// vmcnt(6) once per K-tile (end of p3): retires exactly tile t+1's 8 loads,
// keeps tile t+2's 6-so-far in flight. Never drains to 0 mid-loop.
__global__ __launch_bounds__(512, 2) void k_gemm(const uint16_t* __restrict__ Zb,
                                                 const uint16_t* __restrict__ Tb,
                                                 float* __restrict__ sim) {
  extern __shared__ __attribute__((aligned(16))) char lds[];

  int tid = threadIdx.x;
  int wave = tid >> 6, lane = tid & 63;
  int wm = wave >> 2, wn = wave & 3;
  int brow = (blockIdx.x >> 4) << 8;
  int bcol = (blockIdx.x & 15) << 8;

  f32x4 acc[8][4] = {};

  const uint16_t* gA = Zb + (size_t)brow * DIM + wave * 8;
  const uint16_t* gB = Tb + (size_t)bcol * DIM + wave * 8;
  char* ldsW = lds + (wave << 12);  // this wave's kc slab

  int kqg = lane >> 4;                          // 0..3
  int rbyte = ((wm << 7) + (lane & 15)) << 4;   // A row base byte within kc-slab
  int cbyte = ((wn << 6) + (lane & 15)) << 4;   // B row base byte

  auto SA = [&](int t, int bb, int rg) {
    gll16(gA + (size_t)t * 64 + (size_t)(rg * 64 + lane) * DIM,
          ldsW + bb + rg * 1024);
  };
  auto SB = [&](int t, int bb, int rg) {
    gll16(gB + (size_t)t * 64 + (size_t)(rg * 64 + lane) * DIM,
          ldsW + bb + 32768 + rg * 1024);
  };

  auto LOADB = [&](int bb, short8 (&bf)[2][4]) {
    #pragma unroll
    for (int ks = 0; ks < 2; ++ks) {
      const char* Bb = lds + bb + (((ks << 2) + kqg) << 12) + 32768;
      #pragma unroll
      for (int n = 0; n < 4; ++n)
        bf[ks][n] = *(const short8*)(Bb + cbyte + (n << 8));
    }
  };
  auto AREAD = [&](int bb, int mp, short8 (&af)[2][2]) {
    #pragma unroll
    for (int ks = 0; ks < 2; ++ks) {
      const char* Ab = lds + bb + (((ks << 2) + kqg) << 12);
      af[ks][0] = *(const short8*)(Ab + rbyte + (((mp << 1) + 0) << 8));
      af[ks][1] = *(const short8*)(Ab + rbyte + (((mp << 1) + 1) << 8));
    }
  };
  auto MM = [&](int mp, short8 (&af)[2][2], short8 (&bf)[2][4]) {
    __builtin_amdgcn_s_setprio(1);
    #pragma unroll
    for (int ks = 0; ks < 2; ++ks)
      #pragma unroll
      for (int mm = 0; mm < 2; ++mm)
        #pragma unroll
        for (int n = 0; n < 4; ++n)
          acc[(mp << 1) + mm][n] = __builtin_amdgcn_mfma_f32_16x16x32_bf16(
              af[ks][mm], bf[ks][n], acc[(mp << 1) + mm][n], 0, 0, 0);
    __builtin_amdgcn_s_setprio(0);
  };

#define LGKM0_BAR                                          \
  __builtin_amdgcn_s_barrier();                            \
  asm volatile("s_waitcnt lgkmcnt(0)" ::: "memory");

  // One K-tile: t = tile index, bb = its buffer byte base (0 / 65536),
  // s0: stage A rg1,rg3 of tile t+1 (other buffer), s12: stage tile t+2 (this buffer),
  // vm: trailing vmcnt (6 steady, 0 drain, -1 none).
  auto TILE = [&](int t, int bb, bool s0, bool s12, int vm) {
    short8 bf[2][4], af[2][2];
    // phase 0: B all + A m0-1
    LOADB(bb, bf);
    AREAD(bb, 0, af);
    if (s0) { SA(t + 1, bb ^ 65536, 1); SA(t + 1, bb ^ 65536, 3); }
    LGKM0_BAR;
    MM(0, af, bf);
    __builtin_amdgcn_s_barrier();
    // phase 1: A m2-3 ; restage B (dead since p0 end)
    AREAD(bb, 1, af);
    if (s12) { SB(t + 2, bb, 0); SB(t + 2, bb, 1); SB(t + 2, bb, 2); SB(t + 2, bb, 3); }
    LGKM0_BAR;
    MM(1, af, bf);
    __builtin_amdgcn_s_barrier();
    // phase 2: A m4-5 ; restage A rg0,rg2 (dead since p1 end)
    AREAD(bb, 2, af);
    if (s12) { SA(t + 2, bb, 0); SA(t + 2, bb, 2); }
    LGKM0_BAR;
    MM(2, af, bf);
    __builtin_amdgcn_s_barrier();
    // phase 3: A m6-7 ; counted vmcnt at tile end
    AREAD(bb, 3, af);
    LGKM0_BAR;
    MM(3, af, bf);
    if (vm == 6) asm volatile("s_waitcnt vmcnt(6)" ::: "memory");
    else if (vm == 0) asm volatile("s_waitcnt vmcnt(0)" ::: "memory");
    __builtin_amdgcn_s_barrier();
  };

  // ---- prologue: stage tiles 0 (buf0) and 1 (buf1); land 0, keep 1 in flight
  #pragma unroll
  for (int rg = 0; rg < 4; ++rg) { SA(0, 0, rg); SB(0, 0, rg); }
  #pragma unroll
  for (int rg = 0; rg < 4; ++rg) { SA(1, 65536, rg); SB(1, 65536, rg); }
  asm volatile("s_waitcnt vmcnt(8)" ::: "memory");
  __builtin_amdgcn_s_barrier();

  // ---- 12 K-tiles (K = 768 = 12 x 64)
  TILE(0, 0, false, true, 6);
  #pragma unroll 1
  for (int t = 1; t <= 9; ++t) TILE(t, (t & 1) << 16, true, true, 6);
  TILE(10, 0, true, false, 0);
  TILE(11, 65536, false, false, -1);

#undef LGKM0_BAR

  // epilogue: C/D layout col=lane&15, row=(lane>>4)*4+reg
  int crow0 = brow + (wm << 7) + ((lane >> 4) << 2);
  int ccol0 = bcol + (wn << 6) + (lane & 15);
  #pragma unroll
  for (int m = 0; m < 8; ++m)
    #pragma unroll
    for (int n = 0; n < 4; ++n)
      #pragma unroll
      for (int r = 0; r < 4; ++r)
        sim[(size_t)(crow0 + m * 16 + r) * BSZ + (ccol0 + n * 16)] = acc[m][n][r];
}

// ---------- K3: tile pass — row & col partial top-5 (branchless, b128, 1 barrier)
// 1024 blocks, 256 threads, 128x128 tile in 64 KiB LDS.
__global__ __launch_bounds__(256) void k_tile(const float* __restrict__ sim,
                                              float* __restrict__ rp,
                                              float* __restrict__ cp) {
  extern __shared__ float l32[];  // 128*128 floats = 64 KiB
  int tid = threadIdx.x;
  int tr = blockIdx.x >> 5, tc = blockIdx.x & 31;
  int row0 = tr << 7, col0 = tc << 7;
  bool diag = (tr == tc);

  // ---- stage: 16 x f32x4 coalesced loads
  int q = tid & 31;   // chunk col 0..31
  int g = tid >> 5;   // row group 0..7
  const float* gsrc = sim + (size_t)(row0 + (g << 4)) * BSZ + col0 + (q << 2);

  f32x4 v[16];
  #pragma unroll
  for (int k = 0; k < 16; ++k)
    v[k] = *(const f32x4*)(gsrc + (size_t)k * BSZ);

  #pragma unroll
  for (int k = 0; k < 16; ++k) {
    int r = (g << 4) + k;
    if (diag && (r >> 2) == q) v[k][r & 3] = -1e30f;  // mask diagonal
    *(f32x4*)(l32 + (r << 7) + ((q ^ (r & 7)) << 2)) = v[k];
  }
  __syncthreads();

  // ---- row scan: 2 threads/row, 64 cols each via 16 x b128
  {
    int row = tid >> 1, h = tid & 1;
    int rx = row & 7;
    const float* rb = l32 + (row << 7);
    float a0 = -1e30f, a1 = -1e30f, a2 = -1e30f, a3 = -1e30f, a4 = -1e30f;
    #pragma unroll
    for (int j = 0; j < 16; ++j) {
      int c16 = (h << 4) + j;
      f32x4 x = *(const f32x4*)(rb + ((c16 ^ rx) << 2));
      sins5(x[0], a0, a1, a2, a3, a4);
      sins5(x[1], a0, a1, a2, a3, a4);
      sins5(x[2], a0, a1, a2, a3, a4);
      sins5(x[3], a0, a1, a2, a3, a4);
    }
    float b0 = __shfl_xor(a0, 1), b1 = __shfl_xor(a1, 1),
          b2 = __shfl_xor(a2, 1), b3 = __shfl_xor(a3, 1),
          b4 = __shfl_xor(a4, 1);
    sins5(b0, a0, a1, a2, a3, a4);
    sins5(b1, a0, a1, a2, a3, a4);
    sins5(b2, a0, a1, a2, a3, a4);
    sins5(b3, a0, a1, a2, a3, a4);
    sins5(b4, a0, a1, a2, a3, a4);
    if (h == 0) {
      float* pr = rp + ((size_t)(row0 + row) * 32 + tc) * 5;
      pr[0] = a0; pr[1] = a1; pr[2] = a2; pr[3] = a3; pr[4] = a4;
    }
  }

  // ---- col scan: 2 threads/col, 64 rows each via b32
  {
    int c = tid >> 1, hf = tid & 1;
    int cc = c >> 2, cw = c & 3;
    float a0 = -1e30f, a1 = -1e30f, a2 = -1e30f, a3 = -1e30f, a4 = -1e30f;
    #pragma unroll 8
    for (int k = 0; k < 64; ++k) {
      int r = (hf << 6) + k;
      float x = l32[(r << 7) + (((cc ^ (r & 7)) << 2) | cw)];
      sins5(x, a0, a1, a2, a3, a4);
    }
    float b0 = __shfl_xor(a0, 1), b1 = __shfl_xor(a1, 1),
          b2 = __shfl_xor(a2, 1), b3 = __shfl_xor(a3, 1),
          b4 = __shfl_xor(a4, 1);
    sins5(b0, a0, a1, a2, a3, a4);
    sins5(b1, a0, a1, a2, a3, a4);
    sins5(b2, a0, a1, a2, a3, a4);
    sins5(b3, a0, a1, a2, a3, a4);
    sins5(b4, a0, a1, a2, a3, a4);
    if (hf == 0) {
      float* pc = cp + ((size_t)(col0 + c) * 32 + tr) * 5;
      pc[0] = a0; pc[1] = a1; pc[2] = a2; pc[3] = a3; pc[4] = a4;
    }
  }
}

// ---------- K4: merge partials (wave per line) + loss ----------
__global__ __launch_bounds__(256) void k_merge(const float* __restrict__ sim,
                                               const float* __restrict__ rp,
                                               const float* __restrict__ cp,
                                               float* __restrict__ lossbuf) {
  int wave = threadIdx.x >> 6, lane = threadIdx.x & 63;
  int wid = blockIdx.x * 4 + wave;
  bool isCol = wid >= BSZ;
  int line = isCol ? wid - BSZ : wid;
  const float* src = (isCol ? cp : rp) + (size_t)line * 160;

  float t0 = -1e30f, t1 = -1e30f, t2 = -1e30f, t3 = -1e30f, t4 = -1e30f;
  ins5(src[lane], t0, t1, t2, t3, t4);
  ins5(src[lane + 64], t0, t1, t2, t3, t4);
  if (lane < 32) ins5(src[lane + 128], t0, t1, t2, t3, t4);

  float top[5];
  #pragma unroll
  for (int e = 0; e < 5; e++) {
    float m = t0;
    #pragma unroll
    for (int off = 32; off >= 1; off >>= 1) m = fmaxf(m, __shfl_xor(m, off));
    unsigned long long msk = __ballot(t0 == m);
    int owner = __ffsll(msk) - 1;
    if (lane == owner) { t0 = t1; t1 = t2; t2 = t3; t3 = t4; t4 = -1e30f; }
    top[e] = m;
  }

  if (lane == 0) {
    float pos = sim[(size_t)line * BSZ + line] / TEMP;
    float l0 = top[0] / TEMP, l1 = top[1] / TEMP, l2 = top[2] / TEMP,
          l3 = top[3] / TEMP, l4 = top[4] / TEMP;
    float mx = fmaxf(pos, fmaxf(fmaxf(l0, l1), fmaxf(fmaxf(l2, l3), l4)));
    float s = expf(pos - mx) + expf(l0 - mx) + expf(l1 - mx) +
              expf(l2 - mx) + expf(l3 - mx) + expf(l4 - mx);
    lossbuf[wid] = mx + logf(s) - pos;
  }
}

// ---------- K5: final reduction ----------
__global__ __launch_bounds__(256) void k_reduce(const float* __restrict__ losses,
                                                float* __restrict__ out) {
  int tid = threadIdx.x;
  float s = 0.f;
  for (int i = tid; i < 2 * BSZ; i += 256) s += losses[i];
  #pragma unroll
  for (int off = 32; off >= 1; off >>= 1) s += __shfl_xor(s, off);
  __shared__ float wss[4];
  if ((tid & 63) == 0) wss[tid >> 6] = s;
  __syncthreads();
  if (tid == 0) out[0] = (wss[0] + wss[1] + wss[2] + wss[3]) / (2.0f * BSZ);
}

// ---------- launcher ----------
extern "C" void kernel_launch(void* const* d_in, const int* in_sizes, int n_in,
                              void* d_out, int out_size, void* d_ws, size_t ws_size,
                              hipStream_t stream) {
  const float* text = (const float*)d_in[0];
  const float* table = (const float*)d_in[1];
  float* out = (float*)d_out;
  float* sim = out + 1;  // d_out = [loss, sim(4096x4096)]

  uint16_t* Zb = (uint16_t*)d_ws;
  uint16_t* Tb = Zb + (size_t)BSZ * DIM;
  float* lossbuf = (float*)(Tb + (size_t)BSZ * DIM);  // 2*BSZ floats

  // rp/cp alias the Zb/Tb region (dead after k_gemm; stream-ordered).
  float* rp = (float*)d_ws;                  // [4096][32][5]
  float* cp = rp + (size_t)BSZ * 32 * 5;     // [4096][32][5]

  k_norm<<<2 * BSZ, 256, 0, stream>>>(text, table, Tb, Zb);
  k_gemm<<<(BSZ / 256) * (BSZ / 256), 512, 131072, stream>>>(Zb, Tb, sim);
  k_tile<<<32 * 32, 256, 65536, stream>>>(sim, rp, cp);
  k_merge<<<2 * BSZ / 4, 256, 0, stream>>>(sim, rp, cp, lossbuf);
  k_reduce<<<1, 256, 0, stream>>>(lossbuf, out);
}